// Round 3
// baseline (1017.138 us; speedup 1.0000x reference)
//
#include <hip/hip_runtime.h>

namespace {
constexpr int TK  = 17;
constexpr int TC  = 256;
constexpr int TCI = 64;
constexpr int TG  = 5;
constexpr int XPAD = 4;   // row pad (floats) to spread LDS banks

typedef float v4f __attribute__((ext_vector_type(4)));   // native vector for nontemporal builtins

__device__ __forceinline__ float fsilu(float v)    { return v / (1.f + __expf(-v)); }
__device__ __forceinline__ float fsigmoid(float v) { return 1.f / (1.f + __expf(-v)); }
}

__global__ __launch_bounds__(256, 5)
void fused_gnn_kernel(const float* __restrict__ x,
                      const float* __restrict__ Wd,
                      const float* __restrict__ bd,
                      const float* __restrict__ bn1s, const float* __restrict__ bn1b,
                      const float* __restrict__ bn1m, const float* __restrict__ bn1v,
                      const float* __restrict__ Wc,
                      const float* __restrict__ bn2s, const float* __restrict__ bn2b,
                      const float* __restrict__ bn2m, const float* __restrict__ bn2v,
                      const float* __restrict__ Wa, const float* __restrict__ ba,
                      float* __restrict__ out)
{
    __shared__ float xs[TK][TC + XPAD];        // staged x tile, reused in phase F
    __shared__ float xd_s[TK][TCI + XPAD];     // silu(bn1(x@Wd))
    __shared__ float means_s[TG][TCI];
    __shared__ float mw_s[2][TG][TCI];         // mw1, mw2
    __shared__ float agg_s[TG][TCI];

    const int tid = threadIdx.x;
    const int b   = blockIdx.x;
    const float* xb = x + (size_t)b * (TK * TC);

    // ---- stage x (17x256) as float4, coalesced, NON-TEMPORAL (zero cross-block
    //      reuse; keep it out of L2 so the shared weights stay resident) ----
    for (int idx = tid; idx < TK * TC / 4; idx += 256) {
        const int k  = idx >> 6;      // 64 float4 per row
        const int c4 = idx & 63;
        const v4f v = __builtin_nontemporal_load(&((const v4f*)xb)[idx]);
        *(v4f*)&xs[k][c4 * 4] = v;
    }
    __syncthreads();

    const int lane = tid & 63;
    const int wv   = tid >> 6;            // wave 0..3
    const int ksub = lane >> 4;           // 0..3  (4 k-rows per wave)
    const int k    = wv * 4 + ksub;       // 0..15 (k=16 handled by wave 0)
    const int i4   = (lane & 15) * 4;     // 4 consecutive i per lane

    // ---- Phase A: xd[k][i] = sum_c x[k][c] * Wd[c][i] ----
    float acc0 = 0.f, acc1 = 0.f, acc2 = 0.f, acc3 = 0.f;
    float g0 = 0.f, g1 = 0.f, g2 = 0.f, g3 = 0.f;   // k = 16 (wave 0)
    #pragma unroll 8
    for (int c4 = 0; c4 < TC; c4 += 4) {
        const float4 xv = *(const float4*)&xs[k][c4];
        const float4 wA = *(const float4*)&Wd[(c4 + 0) * TCI + i4];
        const float4 wB = *(const float4*)&Wd[(c4 + 1) * TCI + i4];
        const float4 wC = *(const float4*)&Wd[(c4 + 2) * TCI + i4];
        const float4 wD = *(const float4*)&Wd[(c4 + 3) * TCI + i4];
        acc0 += xv.x * wA.x + xv.y * wB.x + xv.z * wC.x + xv.w * wD.x;
        acc1 += xv.x * wA.y + xv.y * wB.y + xv.z * wC.y + xv.w * wD.y;
        acc2 += xv.x * wA.z + xv.y * wB.z + xv.z * wC.z + xv.w * wD.z;
        acc3 += xv.x * wA.w + xv.y * wB.w + xv.z * wC.w + xv.w * wD.w;
        if (wv == 0) {
            const float4 xw = *(const float4*)&xs[16][c4];
            g0 += xw.x * wA.x + xw.y * wB.x + xw.z * wC.x + xw.w * wD.x;
            g1 += xw.x * wA.y + xw.y * wB.y + xw.z * wC.y + xw.w * wD.y;
            g2 += xw.x * wA.z + xw.y * wB.z + xw.z * wC.z + xw.w * wD.z;
            g3 += xw.x * wA.w + xw.y * wB.w + xw.z * wC.w + xw.w * wD.w;
        }
    }
    // bn1 + silu epilogue (fold b_down into bn1 affine)
    {
        const float4 s1  = *(const float4*)&bn1s[i4];
        const float4 v1  = *(const float4*)&bn1v[i4];
        const float4 m1  = *(const float4*)&bn1m[i4];
        const float4 bb1 = *(const float4*)&bn1b[i4];
        const float4 bd4 = *(const float4*)&bd[i4];
        const float a1x = s1.x * rsqrtf(v1.x + 1e-5f);
        const float a1y = s1.y * rsqrtf(v1.y + 1e-5f);
        const float a1z = s1.z * rsqrtf(v1.z + 1e-5f);
        const float a1w = s1.w * rsqrtf(v1.w + 1e-5f);
        const float b1x = (bd4.x - m1.x) * a1x + bb1.x;
        const float b1y = (bd4.y - m1.y) * a1y + bb1.y;
        const float b1z = (bd4.z - m1.z) * a1z + bb1.z;
        const float b1w = (bd4.w - m1.w) * a1w + bb1.w;
        float4 r;
        r.x = fsilu(acc0 * a1x + b1x);
        r.y = fsilu(acc1 * a1y + b1y);
        r.z = fsilu(acc2 * a1z + b1z);
        r.w = fsilu(acc3 * a1w + b1w);
        *(float4*)&xd_s[k][i4] = r;
        if (wv == 0 && lane < 16) {
            float4 r2;
            r2.x = fsilu(g0 * a1x + b1x);
            r2.y = fsilu(g1 * a1y + b1y);
            r2.z = fsilu(g2 * a1z + b1z);
            r2.w = fsilu(g3 * a1w + b1w);
            *(float4*)&xd_s[16][i4] = r2;
        }
    }
    __syncthreads();

    // ---- Phase B1: group means (g is wave-uniform in both passes) ----
    for (int u = tid; u < TG * TCI; u += 256) {
        const int g = u >> 6, i = u & 63;
        float m;
        if (g == 0) {
            m = (xd_s[0][i] + xd_s[1][i] + xd_s[2][i] + xd_s[3][i] + xd_s[4][i]) * 0.2f;
        } else {
            const int base = (g == 1) ? 5 : (g == 2) ? 6 : (g == 3) ? 11 : 12;
            m = (xd_s[base][i] + xd_s[base + 2][i] + xd_s[base + 4][i]) * (1.f / 3.f);
        }
        means_s[g][i] = m;
    }
    __syncthreads();

    // ---- Phase B2: mw1[g][o] = means[g] . Wc[o][0:64]; mw2 over Wc[o][64:128] ----
    for (int u = tid; u < 2 * TG * TCI; u += 256) {
        const int which = (u >= TG * TCI) ? 1 : 0;
        const int rem   = u - which * TG * TCI;
        const int g = rem >> 6, o = rem & 63;
        const float4* wrow = (const float4*)&Wc[o * (2 * TCI) + which * TCI];
        const float4* mrow = (const float4*)&means_s[g][0];
        float s = 0.f;
        #pragma unroll
        for (int t = 0; t < TCI / 4; ++t) {
            const float4 w4 = wrow[t];
            const float4 m4 = mrow[t];
            s += m4.x * w4.x + m4.y * w4.y + m4.z * w4.z + m4.w * w4.w;
        }
        mw_s[which][g][o] = s;
    }
    __syncthreads();

    // ---- Phase B3: agg[g][o] = sum_{c!=g} silu(bn2(mw1[g]-mw2[g]+mw2[c])) ----
    for (int u = tid; u < TG * TCI; u += 256) {
        const int g = u >> 6, o = u & 63;
        const float a2 = bn2s[o] * rsqrtf(bn2v[o] + 1e-5f);
        const float b2 = bn2b[o] - bn2m[o] * a2;
        const float base = mw_s[0][g][o] - mw_s[1][g][o];
        float s = 0.f;
        #pragma unroll
        for (int cc = 0; cc < TG; ++cc) {
            if (cc == g) continue;
            const float z = (base + mw_s[1][cc][o]) * a2 + b2;
            s += fsilu(z);
        }
        agg_s[g][o] = s;
    }
    __syncthreads();

    // ---- Phase E: att[g][c] = sigmoid(agg[g] . Wa[:,c] + ba[c]) ----
    const int c = tid;
    float e0 = 0.f, e1 = 0.f, e2 = 0.f, e3 = 0.f, e4 = 0.f;
    #pragma unroll 8
    for (int i = 0; i < TCI; ++i) {
        const float w = Wa[i * TC + c];
        e0 += agg_s[0][i] * w;
        e1 += agg_s[1][i] * w;
        e2 += agg_s[2][i] * w;
        e3 += agg_s[3][i] * w;
        e4 += agg_s[4][i] * w;
    }
    const float bac = ba[c];
    float att[TG];
    att[0] = fsigmoid(e0 + bac);
    att[1] = fsigmoid(e1 + bac);
    att[2] = fsigmoid(e2 + bac);
    att[3] = fsigmoid(e3 + bac);
    att[4] = fsigmoid(e4 + bac);

    // ---- Phase F: out[k][c] = x[k][c] * att[group(k)][c], non-temporal stores ----
    float* ob = out + (size_t)b * (TK * TC);
    constexpr int GOF[TK] = {0,0,0,0,0, 1,2,1,2,1, 2,3,4,3,4, 3,4};
    #pragma unroll
    for (int kk = 0; kk < TK; ++kk) {
        __builtin_nontemporal_store(xs[kk][c] * att[GOF[kk]], &ob[kk * TC + c]);
    }
}

extern "C" void kernel_launch(void* const* d_in, const int* in_sizes, int n_in,
                              void* d_out, int out_size, void* d_ws, size_t ws_size,
                              hipStream_t stream) {
    (void)n_in; (void)out_size; (void)d_ws; (void)ws_size;
    const float* x   = (const float*)d_in[0];
    const float* Wd  = (const float*)d_in[1];
    const float* bd  = (const float*)d_in[2];
    const float* s1  = (const float*)d_in[3];
    const float* b1  = (const float*)d_in[4];
    const float* m1  = (const float*)d_in[5];
    const float* v1  = (const float*)d_in[6];
    const float* Wc  = (const float*)d_in[7];
    const float* s2  = (const float*)d_in[8];
    const float* b2  = (const float*)d_in[9];
    const float* m2  = (const float*)d_in[10];
    const float* v2  = (const float*)d_in[11];
    const float* Wa  = (const float*)d_in[12];
    const float* ba  = (const float*)d_in[13];

    const int B = in_sizes[0] / (17 * 256);
    fused_gnn_kernel<<<B, 256, 0, stream>>>(x, Wd, bd, s1, b1, m1, v1,
                                            Wc, s2, b2, m2, v2, Wa, ba,
                                            (float*)d_out);
}

// Round 4
// 58.857 us; speedup vs baseline: 17.2815x; 17.2815x over previous
//
#include <hip/hip_runtime.h>

typedef float  v4f    __attribute__((ext_vector_type(4)));
typedef float  f32x4  __attribute__((ext_vector_type(4)));
typedef short  bf16x8 __attribute__((ext_vector_type(8)));
typedef short  bf16x4 __attribute__((ext_vector_type(4)));

namespace {
// LDS byte offsets (all 16B-aligned; row strides 16B-multiples for b128 ops)
constexpr int OFF_XALL = 0;              // f32  [68][260]  staged x (phase F)
constexpr int OFF_XBF  = 70720;          // bf16 [80][264]  staged x (phase A frags; rows 68-79 garbage, discarded)
constexpr int OFF_MBF  = 112960;         // bf16 [32][72]   means (rows 20-31 garbage)
constexpr int OFF_ABF  = 117568;         // bf16 [32][72]   agg   (rows 20-31 garbage)
constexpr int OFF_R    = 122176;         // union: xd f32[68][66] | mw f32[20][132] | att f32[20][258]
constexpr int OFF_A1   = 142816;         // f32[64] bn1 scale'
constexpr int OFF_B1   = 143072;         // f32[64] bn1 bias' (b_down folded)
constexpr int OFF_A2   = 143328;         // f32[64] bn2 scale'
constexpr int OFF_B2   = 143584;         // f32[64] bn2 bias'
constexpr int LDS_BYTES = 143840;

__device__ __forceinline__ float fsilu(float v){ return v/(1.f+__expf(-v)); }
__device__ __forceinline__ float fsigm(float v){ return 1.f/(1.f+__expf(-v)); }
__device__ __forceinline__ short f2bf(float f){          // fp32 -> bf16 RNE
  unsigned u = __builtin_bit_cast(unsigned, f);
  return (short)((u + 0x7FFFu + ((u>>16)&1u)) >> 16);
}
}

__global__ __launch_bounds__(1024)
void fused_gnn_v3(const float* __restrict__ x,
                  const float* __restrict__ Wd, const float* __restrict__ bd,
                  const float* __restrict__ bn1s, const float* __restrict__ bn1b,
                  const float* __restrict__ bn1m, const float* __restrict__ bn1v,
                  const float* __restrict__ Wc,
                  const float* __restrict__ bn2s, const float* __restrict__ bn2b,
                  const float* __restrict__ bn2m, const float* __restrict__ bn2v,
                  const float* __restrict__ Wa, const float* __restrict__ ba,
                  float* __restrict__ out, int nb, int nit)
{
  extern __shared__ char smem[];
  float* xall = (float*)(smem + OFF_XALL);
  short* xbf  = (short*)(smem + OFF_XBF);
  short* mbf  = (short*)(smem + OFF_MBF);
  short* abf  = (short*)(smem + OFF_ABF);
  float* xd   = (float*)(smem + OFF_R);
  float* mw   = (float*)(smem + OFF_R);
  float* att  = (float*)(smem + OFF_R);
  float* a1   = (float*)(smem + OFF_A1);
  float* b1f  = (float*)(smem + OFF_B1);
  float* a2   = (float*)(smem + OFF_A2);
  float* b2f  = (float*)(smem + OFF_B2);

  const int tid  = threadIdx.x;
  const int l    = tid & 63;
  const int wv   = tid >> 6;        // wave 0..15
  const int arow = l & 15;          // MFMA A row / C col within tile
  const int ak   = (l >> 4) * 8;    // MFMA k-offset within 32-K tile

  // ---- one-time: fold BN affines (b_down folded into bn1 bias) ----
  if (tid < 64) {
    float av = bn1s[tid] * rsqrtf(bn1v[tid] + 1e-5f);
    a1[tid] = av; b1f[tid] = (bd[tid] - bn1m[tid])*av + bn1b[tid];
    float av2 = bn2s[tid] * rsqrtf(bn2v[tid] + 1e-5f);
    a2[tid] = av2; b2f[tid] = bn2b[tid] - bn2m[tid]*av2;
  }

  // ---- one-time: weight B-fragments into registers ----
  // Phase A: B[k][n] = Wd[k][n]; wave's n-tile = wv&3
  const int ntA = wv & 3;
  const int bnA = ntA*16 + arow;
  bf16x8 Bd[8];
  #pragma unroll
  for (int ks = 0; ks < 8; ++ks) {
    bf16x8 f;
    #pragma unroll
    for (int j = 0; j < 8; ++j) f[j] = f2bf(Wd[(ks*32 + ak + j)*64 + bnA]);
    Bd[ks] = f;
  }
  // Phase B2: B[i][(w,o)] = Wc[o][w*64+i]; wave's n-tile = wv&7 (N=128)
  const int colC = (wv & 7)*16 + arow;
  const int cw = colC >> 6, co = colC & 63;
  bf16x8 Bc[2];
  #pragma unroll
  for (int ks = 0; ks < 2; ++ks) {
    bf16x8 f;
    #pragma unroll
    for (int j = 0; j < 8; ++j) f[j] = f2bf(Wc[co*128 + cw*64 + ks*32 + ak + j]);
    Bc[ks] = f;
  }
  // Phase E: B[i][c] = Wa[i][c]; wave's n-tile = wv (N=256)
  const int colE = wv*16 + arow;
  bf16x8 Ba[2];
  #pragma unroll
  for (int ks = 0; ks < 2; ++ks) {
    bf16x8 f;
    #pragma unroll
    for (int j = 0; j < 8; ++j) f[j] = f2bf(Wa[(ks*32 + ak + j)*256 + colE]);
    Ba[ks] = f;
  }

  // ---- T14 staging regs: 4352 float4 per 4-batch iter / 1024 threads ----
  v4f xr0, xr1, xr2, xr3, xr4;
  const v4f* x4 = (const v4f*)x;
  const size_t base4 = (size_t)blockIdx.x * nb * 1088;   // 1088 f4 per batch
  {
    size_t s0 = base4;
    xr0 = x4[s0 + tid];
    xr1 = x4[s0 + 1024 + tid];
    xr2 = x4[s0 + 2048 + tid];
    xr3 = x4[s0 + 3072 + tid];
    if (tid < 256) xr4 = x4[s0 + 4096 + tid];
  }

  for (int it = 0; it < nit; ++it) {
    // ---- write staged x into LDS (fp32 + bf16 copies) ----
    {
      #define STORE_X(REG, IDX) { const int r_ = (IDX)>>6, c4_ = ((IDX)&63)*4;      \
          *(v4f*)&xall[r_*260 + c4_] = (REG);                                       \
          bf16x4 bv_; bv_[0]=f2bf((REG).x); bv_[1]=f2bf((REG).y);                   \
          bv_[2]=f2bf((REG).z); bv_[3]=f2bf((REG).w);                               \
          *(bf16x4*)&xbf[r_*264 + c4_] = bv_; }
      STORE_X(xr0, tid)
      STORE_X(xr1, 1024 + tid)
      STORE_X(xr2, 2048 + tid)
      STORE_X(xr3, 3072 + tid)
      if (tid < 256) STORE_X(xr4, 4096 + tid)
      #undef STORE_X
    }
    // issue next-iter global loads (overlap with this iter's compute)
    if (it + 1 < nit) {
      size_t s0 = base4 + (size_t)(it+1)*4*1088;
      xr0 = x4[s0 + tid];
      xr1 = x4[s0 + 1024 + tid];
      xr2 = x4[s0 + 2048 + tid];
      xr3 = x4[s0 + 3072 + tid];
      if (tid < 256) xr4 = x4[s0 + 4096 + tid];
    }
    __syncthreads();

    // ---- Phase A (MFMA): xd = silu(bn1(x @ Wd)), M=68(+pad), N=64, K=256 ----
    {
      const int mt = wv >> 2;                     // main m-tile 0..3
      f32x4 accM = {0.f,0.f,0.f,0.f};
      f32x4 accT = {0.f,0.f,0.f,0.f};
      #pragma unroll
      for (int ks = 0; ks < 8; ++ks) {
        bf16x8 a = *(const bf16x8*)&xbf[(mt*16 + arow)*264 + ks*32 + ak];
        accM = __builtin_amdgcn_mfma_f32_16x16x32_bf16(a, Bd[ks], accM, 0, 0, 0);
      }
      if (wv < 4) {                               // tail m-tile 4 (rows 64..67)
        #pragma unroll
        for (int ks = 0; ks < 8; ++ks) {
          bf16x8 a = *(const bf16x8*)&xbf[(64 + arow)*264 + ks*32 + ak];
          accT = __builtin_amdgcn_mfma_f32_16x16x32_bf16(a, Bd[ks], accT, 0, 0, 0);
        }
      }
      const int i = ntA*16 + arow;
      const float a1v = a1[i], b1v = b1f[i];
      #pragma unroll
      for (int j = 0; j < 4; ++j) {
        int r = mt*16 + (l>>4)*4 + j;
        if (r < 68) xd[r*66 + i] = fsilu(accM[j]*a1v + b1v);
      }
      if (wv < 4) {
        #pragma unroll
        for (int j = 0; j < 4; ++j) {
          int r = 64 + (l>>4)*4 + j;
          if (r < 68) xd[r*66 + i] = fsilu(accT[j]*a1v + b1v);
        }
      }
    }
    __syncthreads();

    // ---- Phase B1: group means -> bf16 (rows qg = q*5+g, 20 total) ----
    {
      #pragma unroll
      for (int pass = 0; pass < 2; ++pass) {
        int u = pass*1024 + tid;
        if (u < 1280) {
          int qg = u >> 6, i = u & 63;
          int q = qg / 5, g = qg - q*5;
          int rb = q*17;
          float m;
          if (g == 0) {
            m = (xd[(rb+0)*66+i]+xd[(rb+1)*66+i]+xd[(rb+2)*66+i]
                +xd[(rb+3)*66+i]+xd[(rb+4)*66+i])*0.2f;
          } else {
            int kb = rb + ((g==1)?5:(g==2)?6:(g==3)?11:12);
            m = (xd[kb*66+i] + xd[(kb+2)*66+i] + xd[(kb+4)*66+i]) * (1.f/3.f);
          }
          mbf[qg*72 + i] = f2bf(m);
        }
      }
    }
    __syncthreads();

    // ---- Phase B2 (MFMA): mw[qg][(w,o)] = means @ Wc-halves, M=20,N=128,K=64 ----
    {
      const int mt = wv >> 3;                     // 0..1
      f32x4 acc = {0.f,0.f,0.f,0.f};
      #pragma unroll
      for (int ks = 0; ks < 2; ++ks) {
        bf16x8 a = *(const bf16x8*)&mbf[(mt*16 + arow)*72 + ks*32 + ak];
        acc = __builtin_amdgcn_mfma_f32_16x16x32_bf16(a, Bc[ks], acc, 0, 0, 0);
      }
      #pragma unroll
      for (int j = 0; j < 4; ++j) {
        int qg = mt*16 + (l>>4)*4 + j;
        if (qg < 20) mw[qg*132 + colC] = acc[j];
      }
    }
    __syncthreads();

    // ---- Phase B3: agg[qg][o] = sum_{cc!=g} silu(bn2(mw1[g]-mw2[g]+mw2[cc])) ----
    {
      #pragma unroll
      for (int pass = 0; pass < 2; ++pass) {
        int u = pass*1024 + tid;
        if (u < 1280) {
          int qg = u >> 6, o = u & 63;
          int q = qg / 5, g = qg - q*5;
          float bse = mw[qg*132 + o] - mw[qg*132 + 64 + o];
          float av = a2[o], bv = b2f[o];
          float s = 0.f;
          #pragma unroll
          for (int cc = 0; cc < 5; ++cc) {
            if (cc != g) s += fsilu((bse + mw[(q*5+cc)*132 + 64 + o])*av + bv);
          }
          abf[qg*72 + o] = f2bf(s);
        }
      }
    }
    __syncthreads();

    // ---- Phase E (MFMA): att = sigmoid(agg @ Wa + ba), M=20,N=256,K=64 ----
    {
      f32x4 accE0 = {0.f,0.f,0.f,0.f}, accE1 = {0.f,0.f,0.f,0.f};
      #pragma unroll
      for (int ks = 0; ks < 2; ++ks) {
        bf16x8 a0 = *(const bf16x8*)&abf[(arow)*72      + ks*32 + ak];
        bf16x8 a1f = *(const bf16x8*)&abf[(16 + arow)*72 + ks*32 + ak];
        accE0 = __builtin_amdgcn_mfma_f32_16x16x32_bf16(a0,  Ba[ks], accE0, 0, 0, 0);
        accE1 = __builtin_amdgcn_mfma_f32_16x16x32_bf16(a1f, Ba[ks], accE1, 0, 0, 0);
      }
      const float bav = ba[colE];
      #pragma unroll
      for (int j = 0; j < 4; ++j) {
        int qg0 = (l>>4)*4 + j;                   // 0..15, always valid
        att[qg0*258 + colE] = fsigm(accE0[j] + bav);
        int qg1 = 16 + (l>>4)*4 + j;
        if (qg1 < 20) att[qg1*258 + colE] = fsigm(accE1[j] + bav);
      }
    }
    __syncthreads();

    // ---- Phase F: out[k][c] = x[k][c] * att[q*5+GOF[k]][c] ----
    {
      const int q = tid >> 8, c = tid & 255;
      float a5[5];
      #pragma unroll
      for (int g = 0; g < 5; ++g) a5[g] = att[(q*5+g)*258 + c];
      const size_t ob = ((size_t)(blockIdx.x*nb) + it*4 + q)*4352 + c;
      const int xr = q*17;
      #pragma unroll
      for (int k = 0; k < 17; ++k) {
        constexpr int GOF[17] = {0,0,0,0,0,1,2,1,2,1,2,3,4,3,4,3,4};
        out[ob + (size_t)k*256] = xall[(xr+k)*260 + c] * a5[GOF[k]];
      }
    }
    __syncthreads();   // protect xall/xbf before next iter's staging writes
  }
}

extern "C" void kernel_launch(void* const* d_in, const int* in_sizes, int n_in,
                              void* d_out, int out_size, void* d_ws, size_t ws_size,
                              hipStream_t stream) {
    (void)n_in; (void)out_size; (void)d_ws; (void)ws_size;
    const float* x   = (const float*)d_in[0];
    const float* Wd  = (const float*)d_in[1];
    const float* bd  = (const float*)d_in[2];
    const float* s1  = (const float*)d_in[3];
    const float* b1  = (const float*)d_in[4];
    const float* m1  = (const float*)d_in[5];
    const float* v1  = (const float*)d_in[6];
    const float* Wc  = (const float*)d_in[7];
    const float* s2  = (const float*)d_in[8];
    const float* b2  = (const float*)d_in[9];
    const float* m2  = (const float*)d_in[10];
    const float* v2  = (const float*)d_in[11];
    const float* Wa  = (const float*)d_in[12];
    const float* ba  = (const float*)d_in[13];

    const int Btot = in_sizes[0] / (17 * 256);   // 4096
    const int GRID = 256;
    const int nb   = Btot / GRID;                // 16 batches per block
    const int nit  = nb / 4;                     // 4 iterations of 4 batches

    hipFuncSetAttribute((const void*)fused_gnn_v3,
                        hipFuncAttributeMaxDynamicSharedMemorySize, LDS_BYTES);
    fused_gnn_v3<<<GRID, 1024, LDS_BYTES, stream>>>(
        x, Wd, bd, s1, b1, m1, v1, Wc, s2, b2, m2, v2, Wa, ba,
        (float*)d_out, nb, nit);
}